// Round 1
// baseline (198.214 us; speedup 1.0000x reference)
//
#include <hip/hip_runtime.h>

// Fused 2-level inverse Haar DWT (UnPatcher, PATCH_SIZE=4) — float4 streaming version.
// Input  x:   [8, 256, 96, 96]  fp32
// Output out: [8, 16, 384, 384] fp32
//
// Each thread: one (b, g, p, qb) with qb indexing a group of 4 consecutive q.
// Reads 16 channels as float4 (16 B/lane nontemporal dwordx4), applies the
// 2-level +/-1 butterfly vectorized over the 4 q-lanes (per-level scale
// 2*S*S == 1), writes a 4x16 output tile as 16 nontemporal float4 stores.
//
// Rationale vs previous version (scalar q): 4B/lane loads gave 256 B/wave
// granules scattered across 16 planes -> ~61% of achievable HBM BW. 16 B/lane
// quadruples the DRAM granule; nt flag avoids polluting L2 (zero reuse kernel).

#define B_  8
#define CIN 256
#define G_  16
#define H_  96
#define W_  96
#define QB  24   // W_/4
#define OW  384

typedef float f4 __attribute__((ext_vector_type(4)));

__global__ __launch_bounds__(256) void idwt2_fused_v4(const float* __restrict__ x,
                                                      float* __restrict__ out) {
    const int N = B_ * G_ * H_ * QB;  // 294,912
    int idx = blockIdx.x * blockDim.x + threadIdx.x;
    if (idx >= N) return;

    int qb = idx % QB;
    int t1 = idx / QB;
    int p  = t1 % H_;
    int t2 = t1 / H_;
    int g  = t2 % G_;
    int b  = t2 / G_;

    const size_t plane = (size_t)H_ * W_;  // 9216
    const float* xin = x + (size_t)b * CIN * plane + (size_t)p * W_ + 4 * (size_t)qb;

    // v[k][m] = x[b, g + 16k + 64m, p, 4qb .. 4qb+3]   (vector over the 4 q's)
    f4 v[4][4];
#pragma unroll
    for (int k = 0; k < 4; ++k) {
#pragma unroll
        for (int m = 0; m < 4; ++m) {
            const f4* src = reinterpret_cast<const f4*>(xin + (size_t)(g + 16 * k + 64 * m) * plane);
            v[k][m] = __builtin_nontemporal_load(src);
        }
    }

    // Level 1 (inner): t[k][dh][dw] = v0 + (-1)^dh v1 + (-1)^dw v2 + (-1)^(dh+dw) v3
    f4 t[4][2][2];
#pragma unroll
    for (int k = 0; k < 4; ++k) {
        f4 u0 = v[k][0] + v[k][1];
        f4 u1 = v[k][0] - v[k][1];
        f4 u2 = v[k][2] + v[k][3];
        f4 u3 = v[k][2] - v[k][3];
        t[k][0][0] = u0 + u2;
        t[k][0][1] = u0 - u2;
        t[k][1][0] = u1 + u3;
        t[k][1][1] = u1 - u3;
    }

    // Level 2 (outer): rowv[r][c] (vector over jq) = out[4p + r, 16qb + 4jq + c]
    f4 rowv[4][4];
#pragma unroll
    for (int dh = 0; dh < 2; ++dh) {
#pragma unroll
        for (int dw = 0; dw < 2; ++dw) {
            f4 a0 = t[0][dh][dw] + t[1][dh][dw];
            f4 a1 = t[0][dh][dw] - t[1][dh][dw];
            f4 a2 = t[2][dh][dw] + t[3][dh][dw];
            f4 a3 = t[2][dh][dw] - t[3][dh][dw];
            rowv[2 * dh + 0][2 * dw + 0] = a0 + a2;
            rowv[2 * dh + 0][2 * dw + 1] = a0 - a2;
            rowv[2 * dh + 1][2 * dw + 0] = a1 + a3;
            rowv[2 * dh + 1][2 * dw + 1] = a1 - a3;
        }
    }

    // Store: 4 rows x 16 contiguous floats (64 B per row), 16B-aligned.
    float* obase = out + ((size_t)(b * G_ + g) * OW + 4 * (size_t)p) * OW + 16 * (size_t)qb;
#pragma unroll
    for (int r = 0; r < 4; ++r) {
#pragma unroll
        for (int jq = 0; jq < 4; ++jq) {
            f4 s;
            s.x = rowv[r][0][jq];
            s.y = rowv[r][1][jq];
            s.z = rowv[r][2][jq];
            s.w = rowv[r][3][jq];
            __builtin_nontemporal_store(s, reinterpret_cast<f4*>(obase + (size_t)r * OW + 4 * jq));
        }
    }
}

extern "C" void kernel_launch(void* const* d_in, const int* in_sizes, int n_in,
                              void* d_out, int out_size, void* d_ws, size_t ws_size,
                              hipStream_t stream) {
    const float* x = (const float*)d_in[0];
    float* out = (float*)d_out;
    const int N = B_ * G_ * H_ * QB;          // 294,912
    const int block = 256;
    const int grid = (N + block - 1) / block; // 1152
    idwt2_fused_v4<<<grid, block, 0, stream>>>(x, out);
}

// Round 2
// 137.297 us; speedup vs baseline: 1.4437x; 1.4437x over previous
//
#include <hip/hip_runtime.h>

// Fused 2-level inverse Haar DWT (UnPatcher, PATCH_SIZE=4) — float4, cached stores.
// Input  x:   [8, 256, 96, 96]  fp32
// Output out: [8, 16, 384, 384] fp32
//
// Each thread: one (b, g, p, qb) with qb indexing a group of 4 consecutive q.
// Reads 16 channels as float4 (16 B/lane dwordx4 = 1 KB/wave per instruction),
// applies the 2-level +/-1 butterfly vectorized over the 4 q-lanes (per-level
// scale 2*S*S == 1), writes a 4x16 output tile as 16 float4 stores.
//
// v4 post-mortem: nontemporal stores + 64B lane-stride store pattern caused
// partial-line HBM writes -> WRITE_SIZE 2.3x ideal (169 MB vs 75.5 MB), 112 us.
// v5: identical structure, NO nontemporal hints — L2 write-combines the four
// jq-stores into full lines. Loads keep the 16 B/lane granularity win.

#define B_  8
#define CIN 256
#define G_  16
#define H_  96
#define W_  96
#define QB  24   // W_/4
#define OW  384

typedef float f4 __attribute__((ext_vector_type(4)));

__global__ __launch_bounds__(256) void idwt2_fused_v5(const float* __restrict__ x,
                                                      float* __restrict__ out) {
    const int N = B_ * G_ * H_ * QB;  // 294,912
    int idx = blockIdx.x * blockDim.x + threadIdx.x;
    if (idx >= N) return;

    int qb = idx % QB;
    int t1 = idx / QB;
    int p  = t1 % H_;
    int t2 = t1 / H_;
    int g  = t2 % G_;
    int b  = t2 / G_;

    const size_t plane = (size_t)H_ * W_;  // 9216
    const float* xin = x + (size_t)b * CIN * plane + (size_t)p * W_ + 4 * (size_t)qb;

    // v[k][m] = x[b, g + 16k + 64m, p, 4qb .. 4qb+3]   (vector over the 4 q's)
    f4 v[4][4];
#pragma unroll
    for (int k = 0; k < 4; ++k) {
#pragma unroll
        for (int m = 0; m < 4; ++m) {
            v[k][m] = *reinterpret_cast<const f4*>(xin + (size_t)(g + 16 * k + 64 * m) * plane);
        }
    }

    // Level 1 (inner): t[k][dh][dw] = v0 + (-1)^dh v1 + (-1)^dw v2 + (-1)^(dh+dw) v3
    f4 t[4][2][2];
#pragma unroll
    for (int k = 0; k < 4; ++k) {
        f4 u0 = v[k][0] + v[k][1];
        f4 u1 = v[k][0] - v[k][1];
        f4 u2 = v[k][2] + v[k][3];
        f4 u3 = v[k][2] - v[k][3];
        t[k][0][0] = u0 + u2;
        t[k][0][1] = u0 - u2;
        t[k][1][0] = u1 + u3;
        t[k][1][1] = u1 - u3;
    }

    // Level 2 (outer): rowv[r][c] (vector over jq) = out[4p + r, 16qb + 4jq + c]
    f4 rowv[4][4];
#pragma unroll
    for (int dh = 0; dh < 2; ++dh) {
#pragma unroll
        for (int dw = 0; dw < 2; ++dw) {
            f4 a0 = t[0][dh][dw] + t[1][dh][dw];
            f4 a1 = t[0][dh][dw] - t[1][dh][dw];
            f4 a2 = t[2][dh][dw] + t[3][dh][dw];
            f4 a3 = t[2][dh][dw] - t[3][dh][dw];
            rowv[2 * dh + 0][2 * dw + 0] = a0 + a2;
            rowv[2 * dh + 0][2 * dw + 1] = a0 - a2;
            rowv[2 * dh + 1][2 * dw + 0] = a1 + a3;
            rowv[2 * dh + 1][2 * dw + 1] = a1 - a3;
        }
    }

    // Store: 4 rows x 16 contiguous floats (64 B per row), 16B-aligned, cached.
    float* obase = out + ((size_t)(b * G_ + g) * OW + 4 * (size_t)p) * OW + 16 * (size_t)qb;
#pragma unroll
    for (int r = 0; r < 4; ++r) {
#pragma unroll
        for (int jq = 0; jq < 4; ++jq) {
            f4 s;
            s.x = rowv[r][0][jq];
            s.y = rowv[r][1][jq];
            s.z = rowv[r][2][jq];
            s.w = rowv[r][3][jq];
            *reinterpret_cast<f4*>(obase + (size_t)r * OW + 4 * jq) = s;
        }
    }
}

extern "C" void kernel_launch(void* const* d_in, const int* in_sizes, int n_in,
                              void* d_out, int out_size, void* d_ws, size_t ws_size,
                              hipStream_t stream) {
    const float* x = (const float*)d_in[0];
    float* out = (float*)d_out;
    const int N = B_ * G_ * H_ * QB;          // 294,912
    const int block = 256;
    const int grid = (N + block - 1) / block; // 1152
    idwt2_fused_v5<<<grid, block, 0, stream>>>(x, out);
}

// Round 3
// 128.507 us; speedup vs baseline: 1.5424x; 1.0684x over previous
//
#include <hip/hip_runtime.h>

// Fused 2-level inverse Haar DWT (UnPatcher, PATCH_SIZE=4) — multi-g column version.
// Input  x:   [8, 256, 96, 96]  fp32
// Output out: [8, 16, 384, 384] fp32
//
// v5 post-mortem: per-thread 4-consecutive-q f4 loads were re-scalarized by the
// compiler (VGPR_Count=44 < the 64 live floats required), leaving only the
// harmful 64B-lane-stride stores (4x L2 store transactions). Also FETCH_SIZE
// (37MB << 75.5MB input) shows reads are L2/L3-warm -> DRAM read granularity
// was never the limiter; latency hiding + store coalescing are.
//
// v6: baseline-coalesced shapes, 4x work per thread across the g dimension.
// Thread (b, g0, qp) loads all 64 channels ch == g0 (mod 4) at plane offset qp
// (each load instr: consecutive lanes -> consecutive addresses, 256B runs),
// computes 4 independent 16->64 butterflies (per-level scale 2*S*S == 1), and
// writes 4 g-planes x 4 rows of float4 (lane-contiguous 1KB wave stores, same
// as baseline). 4x MLP per wave, 1/4 the index math, VGPR cap 256 to keep the
// 64-float input column live in registers.

#define B_    8
#define CIN   256
#define G_    16
#define H_    96
#define W_    96
#define PLANE 9216   // H_*W_
#define OW    384

__global__ __launch_bounds__(128, 2) void idwt2_fused_v6(const float* __restrict__ x,
                                                         float* __restrict__ out) {
    const int N = B_ * 4 * PLANE;  // 294,912 threads: (b, g0 in [0,4), qp in [0,9216))
    int idx = blockIdx.x * blockDim.x + threadIdx.x;
    if (idx >= N) return;

    int qp  = idx % PLANE;        // = p*96 + q, linear in idx -> coalesced plane access
    int t1  = idx / PLANE;
    int g0  = t1 % 4;
    int b   = t1 / 4;

    int p = qp / W_;
    int q = qp % W_;

    const float* xin = x + (size_t)b * CIN * PLANE + (size_t)qp;

    // vv[s][j] = x[b, (g0+4s) + 16j, p, q]  for s,j: 4 g-groups x 16 taps.
    // All 64 loads independent -> deep MLP; each is a contiguous 256B wave run.
    float vv[4][16];
#pragma unroll
    for (int s = 0; s < 4; ++s) {
#pragma unroll
        for (int j = 0; j < 16; ++j) {
            vv[s][j] = xin[(size_t)(g0 + 4 * s + 16 * j) * PLANE];
        }
    }

#pragma unroll
    for (int s = 0; s < 4; ++s) {
        // Level 1 (inner butterfly): v[k][m] = vv[s][k + 4m]
        float t[4][2][2];
#pragma unroll
        for (int k = 0; k < 4; ++k) {
            float u0 = vv[s][k + 0] + vv[s][k + 4];
            float u1 = vv[s][k + 0] - vv[s][k + 4];
            float u2 = vv[s][k + 8] + vv[s][k + 12];
            float u3 = vv[s][k + 8] - vv[s][k + 12];
            t[k][0][0] = u0 + u2;
            t[k][0][1] = u0 - u2;
            t[k][1][0] = u1 + u3;
            t[k][1][1] = u1 - u3;
        }

        // Level 2 (outer butterfly) -> 4x4 output tile for g-plane g0+4s
        float rowv[4][4];
#pragma unroll
        for (int dh = 0; dh < 2; ++dh) {
#pragma unroll
            for (int dw = 0; dw < 2; ++dw) {
                float a0 = t[0][dh][dw] + t[1][dh][dw];
                float a1 = t[0][dh][dw] - t[1][dh][dw];
                float a2 = t[2][dh][dw] + t[3][dh][dw];
                float a3 = t[2][dh][dw] - t[3][dh][dw];
                rowv[2 * dh + 0][2 * dw + 0] = a0 + a2;
                rowv[2 * dh + 0][2 * dw + 1] = a0 - a2;
                rowv[2 * dh + 1][2 * dw + 0] = a1 + a3;
                rowv[2 * dh + 1][2 * dw + 1] = a1 - a3;
            }
        }

        // Store: 4 rows of float4; consecutive lanes (consecutive q) ->
        // contiguous 1KB wave stores, identical to baseline coalescing.
        float* obase = out + ((size_t)(b * G_ + g0 + 4 * s) * OW + 4 * (size_t)p) * OW
                       + 4 * (size_t)q;
#pragma unroll
        for (int r = 0; r < 4; ++r) {
            float4 f4v = make_float4(rowv[r][0], rowv[r][1], rowv[r][2], rowv[r][3]);
            *reinterpret_cast<float4*>(obase + (size_t)r * OW) = f4v;
        }
    }
}

extern "C" void kernel_launch(void* const* d_in, const int* in_sizes, int n_in,
                              void* d_out, int out_size, void* d_ws, size_t ws_size,
                              hipStream_t stream) {
    const float* x = (const float*)d_in[0];
    float* out = (float*)d_out;
    const int N = B_ * 4 * PLANE;             // 294,912
    const int block = 128;
    const int grid = (N + block - 1) / block; // 2304
    idwt2_fused_v6<<<grid, block, 0, stream>>>(x, out);
}

// Round 4
// 127.249 us; speedup vs baseline: 1.5577x; 1.0099x over previous
//
#include <hip/hip_runtime.h>

// Fused 2-level inverse Haar DWT (UnPatcher, PATCH_SIZE=4) — LDS-transpose version.
// Input  x:   [8, 256, 96, 96]  fp32
// Output out: [8, 16, 384, 384] fp32
//
// v6 post-mortem: 4x per-thread MLP was neutral (~38us) -> not latency/MLP
// bound. All correct-store variants so far used 4B/lane scalar loads (256B/wave
// granules); the 6.29 TB/s copy ceiling uses 16B/lane. v7 decouples load shape
// from store shape via an LDS transpose so BOTH are ideal:
//   load phase:  per block, stage [16 ch][256 qp] (16KB) with dwordx4 loads —
//                each instruction a contiguous 1KB wave run (copy-benchmark shape).
//   compute:     thread t owns qp = qp0+t; reads its 16 channel values from LDS
//                (consecutive lanes -> consecutive banks, conflict-free),
//                butterfly (per-level scale 2*S*S == 1).
//   store phase: 4 float4 rows per thread, contiguous 1KB wave stores (baseline
//                shape, verified WRITE_SIZE == ideal).

#define B_     8
#define CIN    256
#define G_     16
#define PLANE  9216   // 96*96
#define W_     96
#define OW     384
#define CHUNK  256               // qp positions staged per block
#define NCHUNK (PLANE / CHUNK)   // 36

typedef float f4 __attribute__((ext_vector_type(4)));

__global__ __launch_bounds__(256) void idwt2_fused_v7(const float* __restrict__ x,
                                                      float* __restrict__ out) {
    __shared__ f4 lds4[16][CHUNK / 4];  // [j][qp_local/4] = 16 KB

    const int bid   = blockIdx.x;
    const int chunk = bid % NCHUNK;
    const int t1    = bid / NCHUNK;
    const int g     = t1 % G_;
    const int b     = t1 / G_;
    const int qp0   = chunk * CHUNK;

    const int t    = threadIdx.x;
    const int w    = t >> 6;   // wave id 0..3
    const int lane = t & 63;

    // ---- Load phase: 4 x global_load_dwordx4, each a contiguous 1KB wave run.
    // Wave w loads channel-taps j = 4w..4w+3; ch = g + 16j.
    const float* xbase = x + (size_t)b * CIN * PLANE + (size_t)qp0 + 4 * (size_t)lane;
#pragma unroll
    for (int l = 0; l < 4; ++l) {
        const int j  = 4 * w + l;          // 0..15
        const int ch = g + 16 * j;
        lds4[j][lane] = *reinterpret_cast<const f4*>(xbase + (size_t)ch * PLANE);
    }
    __syncthreads();

    // ---- Compute phase: thread t owns qp = qp0 + t.
    const float* ldsf = reinterpret_cast<const float*>(lds4);
    float vv[16];
#pragma unroll
    for (int j = 0; j < 16; ++j) {
        vv[j] = ldsf[j * CHUNK + t];       // lane-consecutive -> bank-conflict-free
    }

    // Level 1 (inner butterfly): v[k][m] = vv[k + 4m]
    float tt[4][2][2];
#pragma unroll
    for (int k = 0; k < 4; ++k) {
        float u0 = vv[k + 0] + vv[k + 4];
        float u1 = vv[k + 0] - vv[k + 4];
        float u2 = vv[k + 8] + vv[k + 12];
        float u3 = vv[k + 8] - vv[k + 12];
        tt[k][0][0] = u0 + u2;
        tt[k][0][1] = u0 - u2;
        tt[k][1][0] = u1 + u3;
        tt[k][1][1] = u1 - u3;
    }

    // Level 2 (outer butterfly) -> 4x4 output tile
    float rowv[4][4];
#pragma unroll
    for (int dh = 0; dh < 2; ++dh) {
#pragma unroll
        for (int dw = 0; dw < 2; ++dw) {
            float a0 = tt[0][dh][dw] + tt[1][dh][dw];
            float a1 = tt[0][dh][dw] - tt[1][dh][dw];
            float a2 = tt[2][dh][dw] + tt[3][dh][dw];
            float a3 = tt[2][dh][dw] - tt[3][dh][dw];
            rowv[2 * dh + 0][2 * dw + 0] = a0 + a2;
            rowv[2 * dh + 0][2 * dw + 1] = a0 - a2;
            rowv[2 * dh + 1][2 * dw + 0] = a1 + a3;
            rowv[2 * dh + 1][2 * dw + 1] = a1 - a3;
        }
    }

    // ---- Store phase: 4 rows of float4; lanes have consecutive qp -> contiguous
    // 1KB wave stores (2 runs max at the 96-wide row wrap).
    const int qp = qp0 + t;
    const int p  = qp / W_;
    const int q  = qp % W_;
    float* obase = out + ((size_t)(b * G_ + g) * OW + 4 * (size_t)p) * OW + 4 * (size_t)q;
#pragma unroll
    for (int r = 0; r < 4; ++r) {
        f4 s;
        s.x = rowv[r][0];
        s.y = rowv[r][1];
        s.z = rowv[r][2];
        s.w = rowv[r][3];
        *reinterpret_cast<f4*>(obase + (size_t)r * OW) = s;
    }
}

extern "C" void kernel_launch(void* const* d_in, const int* in_sizes, int n_in,
                              void* d_out, int out_size, void* d_ws, size_t ws_size,
                              hipStream_t stream) {
    const float* x = (const float*)d_in[0];
    float* out = (float*)d_out;
    const int grid = B_ * G_ * NCHUNK;  // 4608 blocks x 256 threads
    idwt2_fused_v7<<<grid, 256, 0, stream>>>(x, out);
}